// Round 1
// baseline (260.923 us; speedup 1.0000x reference)
//
#include <hip/hip_runtime.h>
#include <math.h>

#define B_ 4
#define H_ 192
#define W_ 192
#define Q_ 160
#define E_ 96
#define M_ 96
#define K_ 4
#define HW_ (H_ * W_)          // 36864
#define NPIX_ (B_ * HW_)       // 147456
#define NBLK_DICE 1024
#define NBUCKET 64

__device__ inline float waveSum(float v) {
    for (int m = 32; m > 0; m >>= 1) v += __shfl_xor(v, m, 64);
    return v;
}
__device__ inline float waveMax(float v) {
    for (int m = 32; m > 0; m >>= 1) v = fmaxf(v, __shfl_xor(v, m, 64));
    return v;
}

// stable softplus = logaddexp(0, x)
__device__ inline float softplusf(float x) {
    return fmaxf(x, 0.f) + log1pf(__expf(-fabsf(x)));
}

// ---------------------------------------------------------------------------
// Fused small kernel:
//  block 0        : class loss   -> ws[0] (sum)
//  block 1        : nll loss     -> ws[2] (sum)
//  blocks 2..385  : 7x7 BCE      -> ws[1] (atomic sum)
//  blocks 386..961: occupancy CE -> ws[3] (atomic sum)
// ---------------------------------------------------------------------------
__global__ __launch_bounds__(256) void small_kernel(
    const float* __restrict__ logit,    // [640]
    const float* __restrict__ trueseg,  // [B,H,W,E]
    const float* __restrict__ binlog,   // [B,H,W,Q]
    const float* __restrict__ inc,      // [B,E,2]
    const float* __restrict__ pos,      // [B,Q,2]
    const float* __restrict__ chol,     // [B,Q,2,2]
    const float* __restrict__ occlog,   // [B,H,W,K]
    const int* __restrict__ occtrue,    // [B,H,W]
    const int* __restrict__ mq,         // [B,M]
    const int* __restrict__ me,         // [B,M]
    float* __restrict__ ws)
{
    __shared__ float red[256];
    __shared__ float lab[B_ * Q_];
    const int tid = threadIdx.x;
    const int blk = blockIdx.x;
    float acc = 0.f;

    if (blk == 0) {
        // ---- class loss ----
        for (int i = tid; i < B_ * Q_; i += 256) lab[i] = 0.f;
        __syncthreads();
        for (int i = tid; i < B_ * M_; i += 256) {
            int b = i / M_;
            lab[b * Q_ + mq[i]] = 1.f;
        }
        __syncthreads();
        for (int i = tid; i < B_ * Q_; i += 256) {
            float x = logit[i];
            float z = lab[i];
            float w = z > 0.f ? 1.f : 0.1f;
            acc += w * (softplusf(x) - x * z);
        }
        red[tid] = acc; __syncthreads();
        for (int s = 128; s > 0; s >>= 1) { if (tid < s) red[tid] += red[tid + s]; __syncthreads(); }
        if (tid == 0) ws[0] = red[0];
    } else if (blk == 1) {
        // ---- distance NLL ----
        for (int i = tid; i < B_ * M_; i += 256) {
            int b = i / M_;
            int qi = mq[i];
            int ei = me[i];
            float px = inc[(b * E_ + ei) * 2 + 0];
            float py = inc[(b * E_ + ei) * 2 + 1];
            float cx = pos[(b * Q_ + qi) * 2 + 0];
            float cy = pos[(b * Q_ + qi) * 2 + 1];
            const float* ch = chol + (size_t)(b * Q_ + qi) * 4;
            float l00 = ch[0], l10 = ch[2], l11 = ch[3];
            float d0 = px - cx, d1 = py - cy;
            float z0 = d0 / l00;
            float z1 = (d1 - l10 * z0) / l11;
            float nll = 0.5f * (z0 * z0 + z1 * z1) + 1.837877066409345f
                        + logf(l00) + logf(l11);
            if (isinf(nll)) nll = 1e7f;
            acc += nll;
        }
        red[tid] = acc; __syncthreads();
        for (int s = 128; s > 0; s >>= 1) { if (tid < s) red[tid] += red[tid + s]; __syncthreads(); }
        if (tid == 0) ws[2] = red[0];
    } else if (blk < 386) {
        // ---- 7x7 window BCE, one block per (b, m) ----
        int idx = blk - 2;          // = b*M_ + m
        int b = idx / M_;
        int ei = me[idx];
        int qi = mq[idx];
        float px = inc[(b * E_ + ei) * 2 + 0];
        float py = inc[(b * E_ + ei) * 2 + 1];
        int r0 = (int)floorf(px) - 3;
        int c0 = (int)floorf(py) - 3;
        if (tid < 49) {
            int rr = r0 + tid / 7;
            int cc = c0 + tid % 7;
            size_t pix = ((size_t)b * H_ + rr) * W_ + cc;
            float tv = trueseg[pix * E_ + ei];
            float lg = binlog[pix * Q_ + qi];
            acc = softplusf(lg) - lg * tv;
        }
        red[tid] = acc; __syncthreads();
        for (int s = 128; s > 0; s >>= 1) { if (tid < s) red[tid] += red[tid + s]; __syncthreads(); }
        if (tid == 0) atomicAdd(&ws[1], red[0]);
    } else {
        // ---- occupancy cross-entropy, 256 pixels per block ----
        int p = (blk - 386) * 256 + tid;
        if (p < NPIX_) {
            float4 v = *(const float4*)(occlog + (size_t)p * 4);
            int lb = occtrue[p];
            float m = fmaxf(fmaxf(v.x, v.y), fmaxf(v.z, v.w));
            float lse = m + __logf(__expf(v.x - m) + __expf(v.y - m) +
                                   __expf(v.z - m) + __expf(v.w - m));
            float xs = lb == 0 ? v.x : (lb == 1 ? v.y : (lb == 2 ? v.z : v.w));
            acc = lse - xs;
        }
        red[tid] = acc; __syncthreads();
        for (int s = 128; s > 0; s >>= 1) { if (tid < s) red[tid] += red[tid + s]; __syncthreads(); }
        if (tid == 0) atomicAdd(&ws[3], red[0]);
    }
}

// ---------------------------------------------------------------------------
// Dice kernel: one wave per pixel. Lane holds channel m=lane, and m=lane+64
// for lane<32 (96 channels). ws[4 + bucket*8 + {0..3}] = num[b] partials,
// ws[4 + bucket*8 + {4..7}] = sum_true[b] partials.
// ---------------------------------------------------------------------------
__global__ __launch_bounds__(256) void dice_kernel(
    const float* __restrict__ trueseg,  // [B,H,W,E]
    const float* __restrict__ por,      // [B,H,W,Q]
    const int* __restrict__ mqall,      // [B,M]
    const int* __restrict__ meall,      // [B,M]
    float* __restrict__ ws)
{
    const int tid = threadIdx.x;
    const int lane = tid & 63;
    const int wid = tid >> 6;
    const int wave = blockIdx.x * 4 + wid;
    const int nwaves = gridDim.x * 4;
    __shared__ float sN[4], sT[4];

    for (int b = 0; b < B_; ++b) {
        const int* mq = mqall + b * M_;
        const int* me = meall + b * M_;
        const int mqa = mq[lane];
        const int mea = me[lane];
        int mqb = 0, meb = 0;
        if (lane < 32) { mqb = mq[64 + lane]; meb = me[64 + lane]; }
        const float* porb = por + (size_t)b * HW_ * Q_;
        const float* trb  = trueseg + (size_t)b * HW_ * E_;

        float an = 0.f, at = 0.f;
        for (int p = wave; p < HW_; p += nwaves) {
            const float* pr = porb + (size_t)p * Q_;
            const float* tr = trb + (size_t)p * E_;
            float p0 = pr[mqa];
            float t0 = tr[mea];
            float p1 = -1e30f, t1 = 0.f;
            if (lane < 32) { p1 = pr[mqb]; t1 = tr[meb]; }
            float mx = waveMax(fmaxf(p0, p1));
            float e0 = __expf(p0 - mx);
            float e1 = (lane < 32) ? __expf(p1 - mx) : 0.f;
            float s  = e0 + e1;
            float se = t0 * e0 + t1 * e1;
            float tt = t0 + t1;
            for (int m2 = 32; m2 > 0; m2 >>= 1) {
                s  += __shfl_xor(s,  m2, 64);
                se += __shfl_xor(se, m2, 64);
                tt += __shfl_xor(tt, m2, 64);
            }
            an += 2.f * se / s;
            at += tt;
        }
        if (lane == 0) { sN[wid] = an; sT[wid] = at; }
        __syncthreads();
        if (tid == 0) {
            float N = sN[0] + sN[1] + sN[2] + sN[3];
            float T = sT[0] + sT[1] + sT[2] + sT[3];
            int bucket = blockIdx.x & (NBUCKET - 1);
            atomicAdd(&ws[4 + bucket * 8 + b], N);
            atomicAdd(&ws[4 + bucket * 8 + 4 + b], T);
        }
        __syncthreads();
    }
}

// ---------------------------------------------------------------------------
// Final combine: one wave. Lane i sums bucket i, butterfly-reduce, lane 0
// assembles the scalar loss.
// ---------------------------------------------------------------------------
__global__ __launch_bounds__(64) void final_kernel(const float* __restrict__ ws,
                                                   float* __restrict__ out)
{
    const int lane = threadIdx.x;
    const float* bk = ws + 4 + lane * 8;
    float n0 = bk[0], n1 = bk[1], n2 = bk[2], n3 = bk[3];
    float t0 = bk[4], t1 = bk[5], t2 = bk[6], t3 = bk[7];
    n0 = waveSum(n0); n1 = waveSum(n1); n2 = waveSum(n2); n3 = waveSum(n3);
    t0 = waveSum(t0); t1 = waveSum(t1); t2 = waveSum(t2); t3 = waveSum(t3);
    if (lane == 0) {
        float class_l = ws[0] * (1.f / (B_ * Q_));
        float bce_l   = ws[1] * (1.f / (B_ * M_ * 49));
        float nll_l   = ws[2] * (1.f / (B_ * M_));
        float occ_l   = ws[3] * (1.f / NPIX_);
        // den_b = sum_true_b + H*W (softmax over m sums to 1 per pixel)
        float dice = 0.f;
        dice += 1.f - (n0 + 1.f) / (t0 + (float)HW_ + 1.f);
        dice += 1.f - (n1 + 1.f) / (t1 + (float)HW_ + 1.f);
        dice += 1.f - (n2 + 1.f) / (t2 + (float)HW_ + 1.f);
        dice += 1.f - (n3 + 1.f) / (t3 + (float)HW_ + 1.f);
        dice *= (1.f / B_);
        out[0] = class_l + bce_l + nll_l + occ_l + dice;
    }
}

extern "C" void kernel_launch(void* const* d_in, const int* in_sizes, int n_in,
                              void* d_out, int out_size, void* d_ws, size_t ws_size,
                              hipStream_t stream) {
    const float* logit   = (const float*)d_in[0];
    const float* trueseg = (const float*)d_in[1];
    const float* binlog  = (const float*)d_in[2];
    const float* por     = (const float*)d_in[3];
    const float* inc     = (const float*)d_in[4];
    const float* pos     = (const float*)d_in[5];
    const float* chol    = (const float*)d_in[6];
    const float* occlog  = (const float*)d_in[7];
    const int*   occtrue = (const int*)d_in[8];
    const int*   mq      = (const int*)d_in[9];
    const int*   me      = (const int*)d_in[10];
    float* out = (float*)d_out;
    float* ws  = (float*)d_ws;

    // zero the accumulators: 4 scalars + 64 buckets * 8 floats
    hipMemsetAsync(d_ws, 0, (4 + NBUCKET * 8) * sizeof(float), stream);

    hipLaunchKernelGGL(small_kernel, dim3(2 + 384 + 576), dim3(256), 0, stream,
                       logit, trueseg, binlog, inc, pos, chol, occlog, occtrue,
                       mq, me, ws);
    hipLaunchKernelGGL(dice_kernel, dim3(NBLK_DICE), dim3(256), 0, stream,
                       trueseg, por, mq, me, ws);
    hipLaunchKernelGGL(final_kernel, dim3(1), dim3(64), 0, stream, ws, out);
}

// Round 3
// 250.332 us; speedup vs baseline: 1.0423x; 1.0423x over previous
//
#include <hip/hip_runtime.h>
#include <math.h>

#define B_ 4
#define H_ 192
#define W_ 192
#define Q_ 160
#define E_ 96
#define M_ 96
#define HW_ (H_ * W_)          // 36864
#define NPIX_ (B_ * HW_)       // 147456
#define NDICE 1024             // dice blocks (4 waves each -> 4096 waves, 9 pixels/wave/batch)
#define NTSUM 1024             // true_segmap streaming-sum blocks (256 per batch)
#define NSMALL 962             // 2 + 384 + 576
#define NBUCKET 64
// ws layout (floats): [0]=class [1]=bce [2]=nll [3]=occ
//   [4   + k*4 + b] k<64 : dice numerator partials
//   [260 + k*4 + b] k<64 : sum_true partials
#define WS_NUM0 4
#define WS_TS0  260
#define WS_TOTAL 516

// ---- DPP wave-64 sum: result lands in lane 63 (rocPRIM sequence) ----
template <int CTRL, int RMASK>
__device__ inline float dpp_add_step(float x) {
    int v = __builtin_amdgcn_update_dpp(0, __float_as_int(x), CTRL, RMASK, 0xF, false);
    return x + __int_as_float(v);
}
__device__ inline float wave_sum63(float x) {
    x = dpp_add_step<0x111, 0xF>(x);  // row_shr:1
    x = dpp_add_step<0x112, 0xF>(x);  // row_shr:2
    x = dpp_add_step<0x114, 0xF>(x);  // row_shr:4
    x = dpp_add_step<0x118, 0xF>(x);  // row_shr:8
    x = dpp_add_step<0x142, 0xA>(x);  // row_bcast:15 -> rows 1,3
    x = dpp_add_step<0x143, 0xC>(x);  // row_bcast:31 -> rows 2,3
    return x;                          // lane 63 = full sum
}

__device__ inline float waveSumAll(float v) {  // broadcast version (small paths only)
    for (int m = 32; m > 0; m >>= 1) v += __shfl_xor(v, m, 64);
    return v;
}

__device__ inline float softplusf(float x) {
    return fmaxf(x, 0.f) + log1pf(__expf(-fabsf(x)));
}

// ---------------------------------------------------------------------------
// One fused kernel. Block regions (dice first = longest pole dispatched first):
//   [0, 1024)        dice numerator
//   [1024, 2048)     sum_true streaming (float4)
//   [2048, 3010)     small: +0 class, +1 nll, +2..385 bce 7x7, +386..961 occ CE
// ---------------------------------------------------------------------------
__global__ __launch_bounds__(256) void fused_kernel(
    const float* __restrict__ logit,    // [640]
    const float* __restrict__ trueseg,  // [B,H,W,E]
    const float* __restrict__ binlog,   // [B,H,W,Q]
    const float* __restrict__ por,      // [B,H,W,Q]
    const float* __restrict__ inc,      // [B,E,2]
    const float* __restrict__ pos,      // [B,Q,2]
    const float* __restrict__ chol,     // [B,Q,2,2]
    const float* __restrict__ occlog,   // [B,H,W,4]
    const int* __restrict__ occtrue,    // [B,H,W]
    const int* __restrict__ mqall,      // [B,M]
    const int* __restrict__ meall,      // [B,M]
    float* __restrict__ ws)
{
    __shared__ float red[256];
    __shared__ float sN[4][B_];
    __shared__ float lab[B_ * Q_];
    const int tid  = threadIdx.x;
    const int lane = tid & 63;
    const int wid  = tid >> 6;
    const int blk  = blockIdx.x;

    if (blk < NDICE) {
        // ================= dice numerator =================
        const int wave = blk * 4 + wid;            // 0..4095
        const bool hi = lane < 32;
        for (int b = 0; b < B_; ++b) {
            const int* mq = mqall + b * M_;
            const int* me = meall + b * M_;
            const int mqa = mq[lane];
            const int mea = me[lane];
            int mqb = 0, meb = 0;
            if (hi) { mqb = mq[64 + lane]; meb = me[64 + lane]; }
            const float* porb = por + (size_t)b * HW_ * Q_;
            const float* trb  = trueseg + (size_t)b * HW_ * E_;
            float an = 0.f;
            // HW_/4096 == 9 iterations for every wave
            #pragma unroll 3
            for (int it = 0; it < 9; ++it) {
                const int p = wave + it * 4096;
                const float* pr = porb + (size_t)p * Q_;
                const float* tr = trb  + (size_t)p * E_;
                float p0 = pr[mqa];
                float t0 = tr[mea];
                float e1 = 0.f, se1 = 0.f;
                if (hi) {
                    float p1 = pr[mqb];
                    float t1 = tr[meb];
                    e1 = __expf(p1);
                    se1 = t1 * e1;
                }
                float e0 = __expf(p0);
                float s  = wave_sum63(e0 + e1);
                float se = wave_sum63(t0 * e0 + se1);
                an += __fdividef(se, s);           // lane 63 holds the real value
            }
            if (lane == 63) sN[wid][b] = an;
        }
        __syncthreads();
        if (tid < B_) {
            float tot = sN[0][tid] + sN[1][tid] + sN[2][tid] + sN[3][tid];
            atomicAdd(&ws[WS_NUM0 + (blk & (NBUCKET - 1)) * 4 + tid], 2.f * tot);
        }
    } else if (blk < NDICE + NTSUM) {
        // ================= sum_true (full tensor sum per batch) =================
        const int j = blk - NDICE;                 // 0..1023
        const int b = j >> 8;                      // 256 blocks per batch
        const float4* t4 = (const float4*)(trueseg + (size_t)b * HW_ * E_);
        const int NF4 = HW_ * E_ / 4;              // 884736
        float a = 0.f;
        for (int idx = (j & 255) * 256 + tid; idx < NF4; idx += 256 * 256) {
            float4 v = t4[idx];
            a += (v.x + v.y) + (v.z + v.w);
        }
        a = wave_sum63(a);
        if (lane == 63) sN[wid][0] = a;
        __syncthreads();
        if (tid == 0) {
            float tot = sN[0][0] + sN[1][0] + sN[2][0] + sN[3][0];
            atomicAdd(&ws[WS_TS0 + (blk & (NBUCKET - 1)) * 4 + b], tot);
        }
    } else {
        const int s = blk - (NDICE + NTSUM);
        float acc = 0.f;
        if (s == 0) {
            // ---- class loss ----
            for (int i = tid; i < B_ * Q_; i += 256) lab[i] = 0.f;
            __syncthreads();
            for (int i = tid; i < B_ * M_; i += 256) {
                int b = i / M_;
                lab[b * Q_ + mqall[i]] = 1.f;
            }
            __syncthreads();
            for (int i = tid; i < B_ * Q_; i += 256) {
                float x = logit[i];
                float z = lab[i];
                float w = z > 0.f ? 1.f : 0.1f;
                acc += w * (softplusf(x) - x * z);
            }
            red[tid] = acc; __syncthreads();
            for (int st = 128; st > 0; st >>= 1) { if (tid < st) red[tid] += red[tid + st]; __syncthreads(); }
            if (tid == 0) ws[0] = red[0];
        } else if (s == 1) {
            // ---- distance NLL ----
            for (int i = tid; i < B_ * M_; i += 256) {
                int b = i / M_;
                int qi = mqall[i];
                int ei = meall[i];
                float px = inc[(b * E_ + ei) * 2 + 0];
                float py = inc[(b * E_ + ei) * 2 + 1];
                float cx = pos[(b * Q_ + qi) * 2 + 0];
                float cy = pos[(b * Q_ + qi) * 2 + 1];
                const float* ch = chol + (size_t)(b * Q_ + qi) * 4;
                float l00 = ch[0], l10 = ch[2], l11 = ch[3];
                float d0 = px - cx, d1 = py - cy;
                float z0 = d0 / l00;
                float z1 = (d1 - l10 * z0) / l11;
                float nll = 0.5f * (z0 * z0 + z1 * z1) + 1.837877066409345f
                            + logf(l00) + logf(l11);
                if (isinf(nll)) nll = 1e7f;
                acc += nll;
            }
            red[tid] = acc; __syncthreads();
            for (int st = 128; st > 0; st >>= 1) { if (tid < st) red[tid] += red[tid + st]; __syncthreads(); }
            if (tid == 0) ws[2] = red[0];
        } else if (s < 386) {
            // ---- 7x7 window BCE, one block per (b, m) ----
            int idx = s - 2;
            int b = idx / M_;
            int ei = meall[idx];
            int qi = mqall[idx];
            float px = inc[(b * E_ + ei) * 2 + 0];
            float py = inc[(b * E_ + ei) * 2 + 1];
            int r0 = (int)floorf(px) - 3;
            int c0 = (int)floorf(py) - 3;
            if (tid < 49) {
                int rr = r0 + tid / 7;
                int cc = c0 + tid % 7;
                size_t pix = ((size_t)b * H_ + rr) * W_ + cc;
                float tv = trueseg[pix * E_ + ei];
                float lg = binlog[pix * Q_ + qi];
                acc = softplusf(lg) - lg * tv;
            }
            red[tid] = acc; __syncthreads();
            for (int st = 128; st > 0; st >>= 1) { if (tid < st) red[tid] += red[tid + st]; __syncthreads(); }
            if (tid == 0) atomicAdd(&ws[1], red[0]);
        } else {
            // ---- occupancy cross-entropy, 256 pixels per block ----
            int p = (s - 386) * 256 + tid;
            if (p < NPIX_) {
                float4 v = *(const float4*)(occlog + (size_t)p * 4);
                int lb = occtrue[p];
                float m = fmaxf(fmaxf(v.x, v.y), fmaxf(v.z, v.w));
                float lse = m + __logf(__expf(v.x - m) + __expf(v.y - m) +
                                       __expf(v.z - m) + __expf(v.w - m));
                float xs = lb == 0 ? v.x : (lb == 1 ? v.y : (lb == 2 ? v.z : v.w));
                acc = lse - xs;
            }
            red[tid] = acc; __syncthreads();
            for (int st = 128; st > 0; st >>= 1) { if (tid < st) red[tid] += red[tid + st]; __syncthreads(); }
            if (tid == 0) atomicAdd(&ws[3], red[0]);
        }
    }
}

// ---------------------------------------------------------------------------
// Final combine: one wave. Lane k owns bucket k.
// ---------------------------------------------------------------------------
__global__ __launch_bounds__(64) void final_kernel(const float* __restrict__ ws,
                                                   float* __restrict__ out)
{
    const int lane = threadIdx.x;
    float n[B_], t[B_];
    for (int b = 0; b < B_; ++b) {
        n[b] = waveSumAll(ws[WS_NUM0 + lane * 4 + b]);
        t[b] = waveSumAll(ws[WS_TS0  + lane * 4 + b]);
    }
    if (lane == 0) {
        float class_l = ws[0] * (1.f / (B_ * Q_));
        float bce_l   = ws[1] * (1.f / (B_ * M_ * 49));
        float nll_l   = ws[2] * (1.f / (B_ * M_));
        float occ_l   = ws[3] * (1.f / NPIX_);
        float dice = 0.f;
        for (int b = 0; b < B_; ++b)
            dice += 1.f - (n[b] + 1.f) / (t[b] + (float)HW_ + 1.f);
        dice *= (1.f / B_);
        out[0] = class_l + bce_l + nll_l + occ_l + dice;
    }
}

extern "C" void kernel_launch(void* const* d_in, const int* in_sizes, int n_in,
                              void* d_out, int out_size, void* d_ws, size_t ws_size,
                              hipStream_t stream) {
    const float* logit   = (const float*)d_in[0];
    const float* trueseg = (const float*)d_in[1];
    const float* binlog  = (const float*)d_in[2];
    const float* por     = (const float*)d_in[3];
    const float* inc     = (const float*)d_in[4];
    const float* pos     = (const float*)d_in[5];
    const float* chol    = (const float*)d_in[6];
    const float* occlog  = (const float*)d_in[7];
    const int*   occtrue = (const int*)d_in[8];
    const int*   mq      = (const int*)d_in[9];
    const int*   me      = (const int*)d_in[10];
    float* out = (float*)d_out;
    float* ws  = (float*)d_ws;

    (void)hipMemsetAsync(d_ws, 0, WS_TOTAL * sizeof(float), stream);

    hipLaunchKernelGGL(fused_kernel, dim3(NDICE + NTSUM + NSMALL), dim3(256), 0, stream,
                       logit, trueseg, binlog, por, inc, pos, chol, occlog, occtrue,
                       mq, me, ws);
    hipLaunchKernelGGL(final_kernel, dim3(1), dim3(64), 0, stream, ws, out);
}